// Round 6
// baseline (704.438 us; speedup 1.0000x reference)
//
#include <hip/hip_runtime.h>
#include <hip/hip_fp16.h>
#include <math.h>

#define NN 2048
#define MM 32
#define DD 768
#define HH 512
#define KT 24   // 768 / 32 k-tiles
constexpr float TEMP = 0.05f;
constexpr float THRESH = 1e-4f;
constexpr float EPS = 1e-6f;

typedef _Float16 halfx8 __attribute__((ext_vector_type(8)));
typedef float floatx4 __attribute__((ext_vector_type(4)));

__device__ __forceinline__ halfx8 habs8(halfx8 a, halfx8 b) {
    halfx8 d = a - b;                     // packed fp16 sub
    union { halfx8 h; unsigned int u[4]; } x;
    x.h = d;
    #pragma unroll
    for (int e = 0; e < 4; ++e) x.u[e] &= 0x7FFF7FFFu;   // packed abs
    return x.h;
}

// ---------------------------------------------------------------------------
// prep_X: X (2048x768 fp32) -> Xf fp16 in MFMA-A fragment order:
// Xf[(it*24 + kt)*64 + lane][e] = X[it*16 + (lane&15)][kt*32 + (lane>>4)*8 + e]
// 196608 vec8 units; grid 192 x 256, 4 units/thread, coalesced 16B writes.
// ---------------------------------------------------------------------------
__global__ __launch_bounds__(256) void prep_X_kernel(
    const float* __restrict__ X, _Float16* __restrict__ Xf)
{
    const int t = threadIdx.x;
    #pragma unroll
    for (int p = 0; p < 4; ++p) {
        int u = blockIdx.x * 1024 + p * 256 + t;
        int it = u / 1536;
        int rem = u - it * 1536;
        int kt = rem >> 6;
        int lane = rem & 63;
        int row = it * 16 + (lane & 15);
        int kb = kt * 32 + (lane >> 4) * 8;
        const float* xp = X + (size_t)row * DD + kb;
        float4 xa = *(const float4*)xp;
        float4 xb = *(const float4*)(xp + 4);
        halfx8 v;
        v[0] = (_Float16)xa.x; v[1] = (_Float16)xa.y;
        v[2] = (_Float16)xa.z; v[3] = (_Float16)xa.w;
        v[4] = (_Float16)xb.x; v[5] = (_Float16)xb.y;
        v[6] = (_Float16)xb.z; v[7] = (_Float16)xb.w;
        *(halfx8*)(Xf + (size_t)u * 8) = v;
    }
}

// ---------------------------------------------------------------------------
// prep_W: 3 W1 blocks (a: rows 0, c: 1536, d: 2304) -> fp16 frag-ordered.
// Wf[wb][kt][nt][lane][j] = W1[rowbase + kt*32 + (lane>>4)*8 + j][nt*16 + (lane&15)]
// ---------------------------------------------------------------------------
__global__ __launch_bounds__(256) void prep_W_kernel(
    const float* __restrict__ W1, _Float16* __restrict__ Wf)
{
    __shared__ float Wt[32 * 512];
    const int wb = blockIdx.x / 24;
    const int kt = blockIdx.x % 24;
    const int rowbase = (wb == 0) ? 0 : (wb == 1 ? 1536 : 2304);
    const int t = threadIdx.x;
    #pragma unroll
    for (int rep = 0; rep < 16; ++rep) {
        int idx = rep * 256 + t;
        int row = idx >> 7;
        int c4 = (idx & 127) * 4;
        *(float4*)&Wt[row * 512 + c4] =
            *(const float4*)(W1 + (size_t)(rowbase + kt * 32 + row) * HH + c4);
    }
    __syncthreads();
    #pragma unroll
    for (int g = 0; g < 8; ++g) {
        halfx8 v;
        #pragma unroll
        for (int jj = 0; jj < 8; ++jj) {
            int o = t * 64 + g * 8 + jj;
            int nt = o >> 9;
            int l  = (o >> 3) & 63;
            int j  = o & 7;
            int k  = ((l >> 4) << 3) + j;
            int n  = nt * 16 + (l & 15);
            v[jj] = (_Float16)Wt[k * 512 + n];
        }
        *(halfx8*)(Wf + ((size_t)wb * KT + kt) * 16384 + t * 64 + g * 8) = v;
    }
}

// ---------------------------------------------------------------------------
// build_A: Arow = X@W1a + |X-q|@W1d, barrier-free MFMA K-loop.
// Block: 32 i x 512 h, 8 waves (each 32i x 64h: rt=2, ct=4). Grid 64.
// ---------------------------------------------------------------------------
__global__ __launch_bounds__(512, 2) void build_A_kernel(
    const float* __restrict__ q, const _Float16* __restrict__ Xf,
    const _Float16* __restrict__ Wf, float* __restrict__ Arow)
{
    __shared__ _Float16 qh[DD];
    const int t = threadIdx.x;
    const int lane = t & 63;
    const int cg = t >> 6;       // 0..7: h-slice of 64
    const int q4 = lane >> 4;
    const int l16 = lane & 15;
    const int i0 = blockIdx.x * 32;

    for (int d = t; d < DD; d += 512) qh[d] = (_Float16)q[d];
    __syncthreads();

    const _Float16* Wa = Wf;
    const _Float16* Wd = Wf + (size_t)2 * KT * 16384;

    floatx4 acc[2][4];
    #pragma unroll
    for (int rt = 0; rt < 2; ++rt)
        #pragma unroll
        for (int ct = 0; ct < 4; ++ct) acc[rt][ct] = (floatx4)0.f;

    for (int kt = 0; kt < KT; ++kt) {
        halfx8 Af[2], Z1[2];
        #pragma unroll
        for (int rt = 0; rt < 2; ++rt) {
            int it = blockIdx.x * 2 + rt;
            Af[rt] = *(const halfx8*)(Xf + ((size_t)(it * 24 + kt) * 64 + lane) * 8);
        }
        halfx8 hq = *(halfx8*)&qh[kt * 32 + q4 * 8];
        #pragma unroll
        for (int rt = 0; rt < 2; ++rt) Z1[rt] = habs8(Af[rt], hq);
        const size_t wo = ((size_t)kt * 32 + cg * 4) * 512 + (size_t)lane * 8;
        #pragma unroll
        for (int ct = 0; ct < 4; ++ct) {
            halfx8 Ba = *(const halfx8*)(Wa + wo + (size_t)ct * 512);
            halfx8 Bd = *(const halfx8*)(Wd + wo + (size_t)ct * 512);
            #pragma unroll
            for (int rt = 0; rt < 2; ++rt) {
                acc[rt][ct] = __builtin_amdgcn_mfma_f32_16x16x32_f16(Af[rt], Ba, acc[rt][ct], 0, 0, 0);
                acc[rt][ct] = __builtin_amdgcn_mfma_f32_16x16x32_f16(Z1[rt], Bd, acc[rt][ct], 0, 0, 0);
            }
        }
    }
    #pragma unroll
    for (int rt = 0; rt < 2; ++rt)
        #pragma unroll
        for (int ct = 0; ct < 4; ++ct)
            #pragma unroll
            for (int reg = 0; reg < 4; ++reg) {
                int row = rt * 16 + q4 * 4 + reg;
                int h = cg * 64 + ct * 16 + l16;
                Arow[(size_t)(i0 + row) * HH + h] = acc[rt][ct][reg];
            }
}

// ---------------------------------------------------------------------------
// build_B: Brow[j][h] = b1[h] + y@W1b + |y-q|@W1e. Grid (32 j, 2 h-chunks).
// ---------------------------------------------------------------------------
__global__ __launch_bounds__(256) void build_B_kernel(
    const float* __restrict__ C_init, const float* __restrict__ q,
    const float* __restrict__ W1, const float* __restrict__ b1,
    float* __restrict__ Brow)
{
    __shared__ float ys[DD], ya[DD];
    const int j = blockIdx.x, t = threadIdx.x;
    const int h = blockIdx.y * 256 + t;
    for (int idx = t; idx < DD; idx += 256) {
        float y = C_init[(size_t)j * DD + idx];
        ys[idx] = y;
        ya[idx] = fabsf(y - q[idx]);
    }
    __syncthreads();
    const float* W1b = W1 + (size_t)768 * HH + h;
    const float* W1e = W1 + (size_t)3072 * HH + h;
    float acc = b1[h];
    #pragma unroll 8
    for (int d = 0; d < DD; ++d)
        acc = fmaf(ys[d], W1b[(size_t)d * HH], fmaf(ya[d], W1e[(size_t)d * HH], acc));
    Brow[(size_t)j * HH + h] = acc;
}

// ---------------------------------------------------------------------------
// pairwise: P(i,j,h) = |x_i - y_j| @ W1c via barrier-free fp16 MFMA, jt=2.
// Block: 64 i x 512 h x 2 j, 8 waves (each 64i x 64h x 2j: rt=4, ct=4, jt=2).
// Grid (32 i, 16 jp) = 512 blocks. Fused relu-dot epilogue -> S.
// ---------------------------------------------------------------------------
__global__ __launch_bounds__(512, 4) void pairwise_kernel(
    const _Float16* __restrict__ Xf, const _Float16* __restrict__ Wf,
    const float* __restrict__ Y,
    const float* __restrict__ Arow, const float* __restrict__ Brow,
    const float* __restrict__ W2, float* __restrict__ S)
{
    __shared__ _Float16 yh[2][DD];
    __shared__ float Sred[2][8][64];
    const int t = threadIdx.x;
    const int lane = t & 63;
    const int cg = t >> 6;       // 0..7: h-slice of 64
    const int q4 = lane >> 4;
    const int l16 = lane & 15;
    const int i0 = blockIdx.x * 64;
    const int j0 = blockIdx.y * 2;

    for (int d = t; d < DD; d += 512) {
        yh[0][d] = (_Float16)Y[(size_t)j0 * DD + d];
        yh[1][d] = (_Float16)Y[(size_t)(j0 + 1) * DD + d];
    }
    __syncthreads();

    const _Float16* Wc = Wf + (size_t)1 * KT * 16384;

    floatx4 acc[2][4][4];   // [jj][rt][ct]
    #pragma unroll
    for (int jj = 0; jj < 2; ++jj)
        #pragma unroll
        for (int rt = 0; rt < 4; ++rt)
            #pragma unroll
            for (int ct = 0; ct < 4; ++ct) acc[jj][rt][ct] = (floatx4)0.f;

    for (int kt = 0; kt < KT; ++kt) {
        halfx8 Af[4], Bf[4], hv[2];
        #pragma unroll
        for (int rt = 0; rt < 4; ++rt) {
            int it = blockIdx.x * 4 + rt;
            Af[rt] = *(const halfx8*)(Xf + ((size_t)(it * 24 + kt) * 64 + lane) * 8);
        }
        hv[0] = *(halfx8*)&yh[0][kt * 32 + q4 * 8];
        hv[1] = *(halfx8*)&yh[1][kt * 32 + q4 * 8];
        const size_t wo = ((size_t)kt * 32 + cg * 4) * 512 + (size_t)lane * 8;
        #pragma unroll
        for (int ct = 0; ct < 4; ++ct)
            Bf[ct] = *(const halfx8*)(Wc + wo + (size_t)ct * 512);
        #pragma unroll
        for (int jj = 0; jj < 2; ++jj) {
            halfx8 Zf[4];
            #pragma unroll
            for (int rt = 0; rt < 4; ++rt) Zf[rt] = habs8(Af[rt], hv[jj]);
            #pragma unroll
            for (int ct = 0; ct < 4; ++ct)
                #pragma unroll
                for (int rt = 0; rt < 4; ++rt)
                    acc[jj][rt][ct] = __builtin_amdgcn_mfma_f32_16x16x32_f16(
                        Zf[rt], Bf[ct], acc[jj][rt][ct], 0, 0, 0);
        }
    }

    // epilogue: relu(P + A + B) . W2, reduce over h
    float w2v[4], bv[2][4];
    #pragma unroll
    for (int ct = 0; ct < 4; ++ct) {
        int h = cg * 64 + ct * 16 + l16;
        w2v[ct] = W2[h];
        bv[0][ct] = Brow[(size_t)j0 * HH + h];
        bv[1][ct] = Brow[(size_t)(j0 + 1) * HH + h];
    }
    #pragma unroll
    for (int jj = 0; jj < 2; ++jj)
        #pragma unroll
        for (int rt = 0; rt < 4; ++rt)
            #pragma unroll
            for (int reg = 0; reg < 4; ++reg) {
                int row = rt * 16 + q4 * 4 + reg;
                const float* ap = Arow + (size_t)(i0 + row) * HH + cg * 64 + l16;
                float s = 0.f;
                #pragma unroll
                for (int ct = 0; ct < 4; ++ct) {
                    float pre = acc[jj][rt][ct][reg] + ap[ct * 16] + bv[jj][ct];
                    s = fmaf(fmaxf(pre, 0.f), w2v[ct], s);
                }
                s += __shfl_xor(s, 1, 64);
                s += __shfl_xor(s, 2, 64);
                s += __shfl_xor(s, 4, 64);
                s += __shfl_xor(s, 8, 64);
                if (l16 == 0) Sred[jj][cg][row] = s;
            }
    __syncthreads();
    if (t < 128) {
        int row = t & 63, jj = t >> 6;
        float s = 0.f;
        #pragma unroll
        for (int g = 0; g < 8; ++g) s += Sred[jj][g][row];
        S[(size_t)(i0 + row) * MM + j0 + jj] = s;
    }
}

// ---------------------------------------------------------------------------
__global__ __launch_bounds__(256) void softmax_kernel(
    const float* __restrict__ S, const float* __restrict__ b2,
    float* __restrict__ a_out)
{
    const int t = threadIdx.x;
    const int j = t & 31, r = t >> 5;
    const int i = blockIdx.x * 8 + r;
    const float b2v = b2[0];
    float s = S[(size_t)i * MM + j];
    float sig = 1.f / (1.f + expf(-(s + b2v)));
    float l = -sig * (1.0f / TEMP);
    float m = l;
    #pragma unroll
    for (int off = 16; off >= 1; off >>= 1) m = fmaxf(m, __shfl_xor(m, off, 32));
    float e = expf(l - m);
    float sum = e;
    #pragma unroll
    for (int off = 16; off >= 1; off >>= 1) sum += __shfl_xor(sum, off, 32);
    a_out[(size_t)i * MM + j] = e / sum;
}

// ---------------------------------------------------------------------------
// cnew: Cacc[j][d] = sum_i a[i][j]*X[i][d]; Asum[j] = sum_i a[i][j].
// Grid (24 d-chunks, 4 j-chunks); thread = (dl=t>>3, jl=t&7). X read once.
// Direct stores, no atomics.
// ---------------------------------------------------------------------------
__global__ __launch_bounds__(256) void cnew_kernel(
    const float* __restrict__ a, const float* __restrict__ X,
    float* __restrict__ Cacc, float* __restrict__ Asum)
{
    const int t = threadIdx.x;
    const int jl = t & 7, dl = t >> 3;
    const int d = blockIdx.x * 32 + dl;
    const int j = blockIdx.y * 8 + jl;
    float acc = 0.f, asum = 0.f;
    #pragma unroll 4
    for (int i = 0; i < NN; ++i) {
        float av = a[(size_t)i * MM + j];
        acc = fmaf(av, X[(size_t)i * DD + d], acc);
        asum += av;
    }
    Cacc[(size_t)j * DD + d] = acc;
    if (blockIdx.x == 0 && dl == 0) Asum[j] = asum;
}

__global__ __launch_bounds__(256) void finalize_kernel(
    const float* __restrict__ Cacc, const float* __restrict__ Asum,
    const float* __restrict__ C_init, float* __restrict__ C_new,
    float* __restrict__ diff)
{
    const int t = threadIdx.x;
    const int d = blockIdx.x * 256 + t;
    const int j = blockIdx.y;
    float c = Cacc[(size_t)j * DD + d] / (Asum[j] + EPS);
    C_new[(size_t)j * DD + d] = c;
    float ad = fabsf(c - C_init[(size_t)j * DD + d]);
    #pragma unroll
    for (int off = 32; off >= 1; off >>= 1) ad += __shfl_xor(ad, off, 64);
    if ((t & 63) == 0) atomicAdd(diff, ad);
}

__global__ __launch_bounds__(256) void select_kernel(
    const float* __restrict__ C_new, const float* __restrict__ C_init,
    const float* __restrict__ diff, float* __restrict__ out)
{
    const int k = blockIdx.x * 256 + threadIdx.x;
    const float dv = *diff;
    out[k] = (dv > THRESH) ? C_new[k] : C_init[k];
}

// ---------------------------------------------------------------------------
extern "C" void kernel_launch(void* const* d_in, const int* in_sizes, int n_in,
                              void* d_out, int out_size, void* d_ws, size_t ws_size,
                              hipStream_t stream)
{
    const float* q      = (const float*)d_in[0];
    const float* X      = (const float*)d_in[1];
    const float* C_init = (const float*)d_in[2];
    const float* W1     = (const float*)d_in[3];
    const float* b1     = (const float*)d_in[4];
    const float* W2     = (const float*)d_in[5];
    const float* b2     = (const float*)d_in[6];

    float* out_C = (float*)d_out;                    // (M, D)
    float* out_a = (float*)d_out + (size_t)MM * DD;  // (N, M)

    float* ws   = (float*)d_ws;
    _Float16* Wf = (_Float16*)ws;                    // 1,179,648 halves = 589,824 floats
    _Float16* Xf = (_Float16*)(ws + 589824);         // 1,572,864 halves = 786,432 floats
    float* Arow = ws + 589824 + 786432;              // N*H
    float* Brow = Arow + (size_t)NN * HH;            // M*H
    float* S    = Brow + (size_t)MM * HH;            // N*M
    float* Cacc = S    + (size_t)NN * MM;            // M*D
    float* Asum = Cacc + (size_t)MM * DD;            // M
    float* diff = Asum + MM;                         // 1 (+15 pad)
    float* Cn   = diff + 16;                         // M*D

    hipMemsetAsync(diff, 0, 16 * sizeof(float), stream);

    prep_X_kernel<<<192, 256, 0, stream>>>(X, Xf);
    prep_W_kernel<<<3 * KT, 256, 0, stream>>>(W1, Wf);
    build_B_kernel<<<dim3(32, 2), 256, 0, stream>>>(C_init, q, W1, b1, Brow);
    build_A_kernel<<<64, 512, 0, stream>>>(q, Xf, Wf, Arow);
    pairwise_kernel<<<dim3(32, 16), 512, 0, stream>>>(Xf, Wf, C_init, Arow, Brow, W2, S);
    softmax_kernel<<<256, 256, 0, stream>>>(S, b2, out_a);
    cnew_kernel<<<dim3(24, 4), 256, 0, stream>>>(out_a, X, Cacc, Asum);
    finalize_kernel<<<dim3(3, 32), 256, 0, stream>>>(Cacc, Asum, C_init, Cn, diff);
    select_kernel<<<96, 256, 0, stream>>>(Cn, C_init, diff, out_C);
}

// Round 8
// 252.917 us; speedup vs baseline: 2.7852x; 2.7852x over previous
//
#include <hip/hip_runtime.h>
#include <hip/hip_fp16.h>
#include <math.h>

#define NN 2048
#define MM 32
#define DD 768
#define HH 512
#define KT 24   // 768 / 32 k-tiles
#define WBLK ((size_t)KT * 16384)   // halves per frag-ordered 768x512 W block
constexpr float TEMP = 0.05f;
constexpr float THRESH = 1e-4f;
constexpr float EPS = 1e-6f;

typedef _Float16 halfx8 __attribute__((ext_vector_type(8)));
typedef float floatx4 __attribute__((ext_vector_type(4)));

__device__ __forceinline__ halfx8 habs8(halfx8 a, halfx8 b) {
    halfx8 d = a - b;
    union { halfx8 h; unsigned int u[4]; } x;
    x.h = d;
    #pragma unroll
    for (int e = 0; e < 4; ++e) x.u[e] &= 0x7FFF7FFFu;
    return x.h;
}

// ---------------------------------------------------------------------------
// prep_X: X -> Xf fp16 MFMA-A frag order:
// Xf[(it*24+kt)*64+lane][e] = X[it*16+(lane&15)][kt*32+(lane>>4)*8+e]
// ---------------------------------------------------------------------------
__global__ __launch_bounds__(256) void prep_X_kernel(
    const float* __restrict__ X, _Float16* __restrict__ Xf)
{
    const int t = threadIdx.x;
    #pragma unroll
    for (int p = 0; p < 4; ++p) {
        int u = blockIdx.x * 1024 + p * 256 + t;
        int it = u / 1536;
        int rem = u - it * 1536;
        int kt = rem >> 6;
        int lane = rem & 63;
        int row = it * 16 + (lane & 15);
        int kb = kt * 32 + (lane >> 4) * 8;
        const float* xp = X + (size_t)row * DD + kb;
        float4 xa = *(const float4*)xp;
        float4 xb = *(const float4*)(xp + 4);
        halfx8 v;
        v[0] = (_Float16)xa.x; v[1] = (_Float16)xa.y;
        v[2] = (_Float16)xa.z; v[3] = (_Float16)xa.w;
        v[4] = (_Float16)xb.x; v[5] = (_Float16)xb.y;
        v[6] = (_Float16)xb.z; v[7] = (_Float16)xb.w;
        *(halfx8*)(Xf + (size_t)u * 8) = v;
    }
}

// ---------------------------------------------------------------------------
// prep_W: all 5 W1 blocks (rowbase = wb*768: a,b,c,d,e) -> fp16 frag order.
// Wf[wb][kt][nt][lane][j] = W1[wb*768+kt*32+(lane>>4)*8+j][nt*16+(lane&15)]
// Grid 120 = 5 x 24.
// ---------------------------------------------------------------------------
__global__ __launch_bounds__(256) void prep_W_kernel(
    const float* __restrict__ W1, _Float16* __restrict__ Wf)
{
    __shared__ float Wt[32 * 512];
    const int wb = blockIdx.x / 24;
    const int kt = blockIdx.x % 24;
    const int rowbase = wb * 768;
    const int t = threadIdx.x;
    #pragma unroll
    for (int rep = 0; rep < 16; ++rep) {
        int idx = rep * 256 + t;
        int row = idx >> 7;
        int c4 = (idx & 127) * 4;
        *(float4*)&Wt[row * 512 + c4] =
            *(const float4*)(W1 + (size_t)(rowbase + kt * 32 + row) * HH + c4);
    }
    __syncthreads();
    #pragma unroll
    for (int g = 0; g < 8; ++g) {
        halfx8 v;
        #pragma unroll
        for (int jj = 0; jj < 8; ++jj) {
            int o = t * 64 + g * 8 + jj;
            int nt = o >> 9;
            int l  = (o >> 3) & 63;
            int j  = o & 7;
            int k  = ((l >> 4) << 3) + j;
            int n  = nt * 16 + (l & 15);
            v[jj] = (_Float16)Wt[k * 512 + n];
        }
        *(halfx8*)(Wf + (size_t)wb * WBLK + (size_t)kt * 16384 + t * 64 + g * 8) = v;
    }
}

// ---------------------------------------------------------------------------
// build_A: Arowh(fp16) = X@W1a + |X-q|@W1d. h-split across blocks.
// Grid (2 hs, 64 by) x 512 thr. Wave: 32i(rt2) x 32h(ct2).
// ---------------------------------------------------------------------------
__global__ __launch_bounds__(512, 2) void build_A_kernel(
    const float* __restrict__ q, const _Float16* __restrict__ Xf,
    const _Float16* __restrict__ Wf, _Float16* __restrict__ Arowh)
{
    __shared__ _Float16 qh[DD];
    const int t = threadIdx.x;
    const int lane = t & 63;
    const int cg = t >> 6;       // 0..7
    const int q4 = lane >> 4;
    const int l16 = lane & 15;
    const int hs = blockIdx.x;   // h-half
    const int by = blockIdx.y;   // i-tile of 32

    for (int d = t; d < DD; d += 512) qh[d] = (_Float16)q[d];
    __syncthreads();

    const _Float16* Wa = Wf;
    const _Float16* Wd = Wf + 3 * WBLK;

    floatx4 acc[2][2];
    #pragma unroll
    for (int rt = 0; rt < 2; ++rt)
        #pragma unroll
        for (int ct = 0; ct < 2; ++ct) acc[rt][ct] = (floatx4)0.f;

    for (int kt = 0; kt < KT; ++kt) {
        halfx8 Af[2], Zd[2];
        #pragma unroll
        for (int rt = 0; rt < 2; ++rt)
            Af[rt] = *(const halfx8*)(Xf + ((size_t)((by * 2 + rt) * 24 + kt) * 64 + lane) * 8);
        halfx8 qf = *(halfx8*)&qh[kt * 32 + q4 * 8];
        #pragma unroll
        for (int rt = 0; rt < 2; ++rt) Zd[rt] = habs8(Af[rt], qf);
        #pragma unroll
        for (int ct = 0; ct < 2; ++ct) {
            int nt = hs * 16 + cg * 2 + ct;
            size_t wo = (size_t)kt * 16384 + (size_t)nt * 512 + (size_t)lane * 8;
            halfx8 Ba = *(const halfx8*)(Wa + wo);
            halfx8 Bd = *(const halfx8*)(Wd + wo);
            #pragma unroll
            for (int rt = 0; rt < 2; ++rt) {
                acc[rt][ct] = __builtin_amdgcn_mfma_f32_16x16x32_f16(Af[rt], Ba, acc[rt][ct], 0, 0, 0);
                acc[rt][ct] = __builtin_amdgcn_mfma_f32_16x16x32_f16(Zd[rt], Bd, acc[rt][ct], 0, 0, 0);
            }
        }
    }
    #pragma unroll
    for (int rt = 0; rt < 2; ++rt)
        #pragma unroll
        for (int ct = 0; ct < 2; ++ct)
            #pragma unroll
            for (int reg = 0; reg < 4; ++reg) {
                int i = by * 32 + rt * 16 + q4 * 4 + reg;
                int h = hs * 256 + cg * 32 + ct * 16 + l16;
                Arowh[(size_t)i * HH + h] = (_Float16)acc[rt][ct][reg];
            }
}

// ---------------------------------------------------------------------------
// build_B (MFMA): Brow[j][h] = b1[h] + y@W1b + |y-q|@W1e.
// Grid 8 h-slabs of 64, 256 thr (4 waves, each 16 h).
// ---------------------------------------------------------------------------
__global__ __launch_bounds__(256) void build_B_kernel(
    const float* __restrict__ C_init, const float* __restrict__ q,
    const _Float16* __restrict__ Wf, const float* __restrict__ b1,
    float* __restrict__ Brow)
{
    __shared__ _Float16 yh[32 * 776];
    __shared__ _Float16 qh[DD];
    const int t = threadIdx.x;
    const int lane = t & 63;
    const int cg = t >> 6;       // 0..3
    const int q4 = lane >> 4;
    const int l16 = lane & 15;
    const int slab = blockIdx.x;

    for (int r = 0; r < 32; ++r)
        for (int d = t; d < DD; d += 256)
            yh[r * 776 + d] = (_Float16)C_init[(size_t)r * DD + d];
    for (int d = t; d < DD; d += 256) qh[d] = (_Float16)q[d];
    __syncthreads();

    const _Float16* Wb = Wf + 1 * WBLK;
    const _Float16* We = Wf + 4 * WBLK;

    floatx4 acc[2];
    acc[0] = (floatx4)0.f; acc[1] = (floatx4)0.f;

    for (int kt = 0; kt < KT; ++kt) {
        halfx8 qf = *(halfx8*)&qh[kt * 32 + q4 * 8];
        halfx8 Ab[2], Ze[2];
        #pragma unroll
        for (int rt = 0; rt < 2; ++rt) {
            Ab[rt] = *(halfx8*)&yh[(rt * 16 + l16) * 776 + kt * 32 + q4 * 8];
            Ze[rt] = habs8(Ab[rt], qf);
        }
        int nt = slab * 4 + cg;
        size_t wo = (size_t)kt * 16384 + (size_t)nt * 512 + (size_t)lane * 8;
        halfx8 Bb = *(const halfx8*)(Wb + wo);
        halfx8 Be = *(const halfx8*)(We + wo);
        #pragma unroll
        for (int rt = 0; rt < 2; ++rt) {
            acc[rt] = __builtin_amdgcn_mfma_f32_16x16x32_f16(Ab[rt], Bb, acc[rt], 0, 0, 0);
            acc[rt] = __builtin_amdgcn_mfma_f32_16x16x32_f16(Ze[rt], Be, acc[rt], 0, 0, 0);
        }
    }
    #pragma unroll
    for (int rt = 0; rt < 2; ++rt)
        #pragma unroll
        for (int reg = 0; reg < 4; ++reg) {
            int j = rt * 16 + q4 * 4 + reg;
            int h = slab * 64 + cg * 16 + l16;
            Brow[(size_t)j * HH + h] = acc[rt][reg] + b1[h];
        }
}

// ---------------------------------------------------------------------------
// pairwise: P = |x_i - y_j| @ W1c, barrier-free fp16 MFMA.
// Block: 64i x 256h (hs half) x 4j, 512 thr = 8 waves.
// Wave: 32i(rt2) x 64h(ct4) x 4j(jt4) -> acc 32 floatx4 = 128.
//   wv = wr*4 + cq: wr in {0,1} (it pair), cq in 0..3 (h quad).
// Coverage: h = hs*256 + cq*64 + ct*16 + l16 over 2hs*4cq*4ct*16 = 512 ✓.
// Partial relu-dot sums atomicAdd'ed into S (S pre-zeroed).
// Grid (16 = hs + 2*jp, 32 it).
// ---------------------------------------------------------------------------
__global__ __launch_bounds__(512, 2) void pairwise_kernel(
    const _Float16* __restrict__ Xf, const _Float16* __restrict__ Wf,
    const float* __restrict__ Y,
    const _Float16* __restrict__ Arowh, const float* __restrict__ Brow,
    const float* __restrict__ W2, float* __restrict__ S)
{
    __shared__ _Float16 yh[4 * DD];     // 6 KB
    __shared__ float Sred[4][4][64];    // 4 KB
    const int t = threadIdx.x;
    const int lane = t & 63;
    const int wv = t >> 6;
    const int wr = wv >> 2;      // 0..1: it pair
    const int cq = wv & 3;       // 0..3: h quad of 64
    const int q4 = lane >> 4;
    const int l16 = lane & 15;
    const int hs = blockIdx.x & 1;
    const int j0 = (blockIdx.x >> 1) * 4;
    const int i0 = blockIdx.y * 64;

    for (int d = t; d < DD; d += 512) {
        #pragma unroll
        for (int jj = 0; jj < 4; ++jj)
            yh[jj * DD + d] = (_Float16)Y[(size_t)(j0 + jj) * DD + d];
    }
    __syncthreads();

    const _Float16* Wc = Wf + 2 * WBLK;

    floatx4 acc[4][2][4];   // [jj][rt][ct]
    #pragma unroll
    for (int jj = 0; jj < 4; ++jj)
        #pragma unroll
        for (int rt = 0; rt < 2; ++rt)
            #pragma unroll
            for (int ct = 0; ct < 4; ++ct) acc[jj][rt][ct] = (floatx4)0.f;

    for (int kt = 0; kt < KT; ++kt) {
        halfx8 Af[2], Bf[4];
        #pragma unroll
        for (int rt = 0; rt < 2; ++rt) {
            int it = blockIdx.y * 4 + wr * 2 + rt;
            Af[rt] = *(const halfx8*)(Xf + ((size_t)(it * 24 + kt) * 64 + lane) * 8);
        }
        #pragma unroll
        for (int ct = 0; ct < 4; ++ct) {
            int nt = hs * 16 + cq * 4 + ct;
            Bf[ct] = *(const halfx8*)(Wc + (size_t)kt * 16384 + (size_t)nt * 512 + (size_t)lane * 8);
        }
        #pragma unroll
        for (int jj = 0; jj < 4; ++jj) {
            halfx8 hv = *(halfx8*)&yh[jj * DD + kt * 32 + q4 * 8];
            halfx8 Zf[2];
            #pragma unroll
            for (int rt = 0; rt < 2; ++rt) Zf[rt] = habs8(Af[rt], hv);
            #pragma unroll
            for (int ct = 0; ct < 4; ++ct)
                #pragma unroll
                for (int rt = 0; rt < 2; ++rt)
                    acc[jj][rt][ct] = __builtin_amdgcn_mfma_f32_16x16x32_f16(
                        Zf[rt], Bf[ct], acc[jj][rt][ct], 0, 0, 0);
        }
    }

    // epilogue: relu(P + A + B) . W2 over this wave's 64-h slice
    float w2v[4], bv[4][4];
    #pragma unroll
    for (int ct = 0; ct < 4; ++ct) {
        int h = hs * 256 + cq * 64 + ct * 16 + l16;
        w2v[ct] = W2[h];
        #pragma unroll
        for (int jj = 0; jj < 4; ++jj)
            bv[jj][ct] = Brow[(size_t)(j0 + jj) * HH + h];
    }
    #pragma unroll
    for (int rt = 0; rt < 2; ++rt)
        #pragma unroll
        for (int reg = 0; reg < 4; ++reg) {
            int row = wr * 32 + rt * 16 + q4 * 4 + reg;
            const _Float16* ap = Arowh + (size_t)(i0 + row) * HH + hs * 256 + cq * 64 + l16;
            float av[4];
            #pragma unroll
            for (int ct = 0; ct < 4; ++ct) av[ct] = (float)ap[ct * 16];
            #pragma unroll
            for (int jj = 0; jj < 4; ++jj) {
                float s = 0.f;
                #pragma unroll
                for (int ct = 0; ct < 4; ++ct) {
                    float pre = acc[jj][rt][ct][reg] + av[ct] + bv[jj][ct];
                    s = fmaf(fmaxf(pre, 0.f), w2v[ct], s);
                }
                s += __shfl_xor(s, 1, 64);
                s += __shfl_xor(s, 2, 64);
                s += __shfl_xor(s, 4, 64);
                s += __shfl_xor(s, 8, 64);
                if (l16 == 0) Sred[jj][cq][row] = s;
            }
        }
    __syncthreads();
    if (t < 256) {
        int row = t & 63, jj = t >> 6;
        float s = Sred[jj][0][row] + Sred[jj][1][row] + Sred[jj][2][row] + Sred[jj][3][row];
        atomicAdd(&S[(size_t)(i0 + row) * MM + j0 + jj], s);
    }
}

// ---------------------------------------------------------------------------
// softmax over j + per-block Asum partials.
// ---------------------------------------------------------------------------
__global__ __launch_bounds__(256) void softmax_kernel(
    const float* __restrict__ S, const float* __restrict__ b2,
    float* __restrict__ a_out, float* __restrict__ Asum)
{
    __shared__ float red[8][32];
    const int t = threadIdx.x;
    const int j = t & 31, r = t >> 5;
    const int i = blockIdx.x * 8 + r;
    const float b2v = b2[0];
    float s = S[(size_t)i * MM + j];
    float sig = 1.f / (1.f + expf(-(s + b2v)));
    float l = -sig * (1.0f / TEMP);
    float m = l;
    #pragma unroll
    for (int off = 16; off >= 1; off >>= 1) m = fmaxf(m, __shfl_xor(m, off, 32));
    float e = expf(l - m);
    float sum = e;
    #pragma unroll
    for (int off = 16; off >= 1; off >>= 1) sum += __shfl_xor(sum, off, 32);
    float av = e / sum;
    a_out[(size_t)i * MM + j] = av;
    red[r][j] = av;
    __syncthreads();
    if (t < 32) {
        float ps = 0.f;
        #pragma unroll
        for (int rr = 0; rr < 8; ++rr) ps += red[rr][t];
        atomicAdd(&Asum[t], ps);
    }
}

// ---------------------------------------------------------------------------
// cnew partials: Cpart[ic][j][d] over 256-i chunks. Grid (12, 8), 256 thr.
// ---------------------------------------------------------------------------
__global__ __launch_bounds__(256) void cnew_part_kernel(
    const float* __restrict__ a, const float* __restrict__ X,
    float* __restrict__ Cpart)
{
    const int t = threadIdx.x;
    const int dl = t & 63, jg = t >> 6;
    const int d = blockIdx.x * 64 + dl;
    const int ic = blockIdx.y;
    const int j0 = jg * 8;
    float acc[8] = {};
    const int ibase = ic * 256;
    #pragma unroll 2
    for (int ii = 0; ii < 256; ++ii) {
        int i = ibase + ii;
        float xv = X[(size_t)i * DD + d];
        float4 a0 = *(const float4*)(a + (size_t)i * MM + j0);
        float4 a1 = *(const float4*)(a + (size_t)i * MM + j0 + 4);
        acc[0] = fmaf(a0.x, xv, acc[0]);
        acc[1] = fmaf(a0.y, xv, acc[1]);
        acc[2] = fmaf(a0.z, xv, acc[2]);
        acc[3] = fmaf(a0.w, xv, acc[3]);
        acc[4] = fmaf(a1.x, xv, acc[4]);
        acc[5] = fmaf(a1.y, xv, acc[5]);
        acc[6] = fmaf(a1.z, xv, acc[6]);
        acc[7] = fmaf(a1.w, xv, acc[7]);
    }
    #pragma unroll
    for (int jj = 0; jj < 8; ++jj)
        Cpart[((size_t)ic * MM + j0 + jj) * DD + d] = acc[jj];
}

// ---------------------------------------------------------------------------
// merge partials -> C_new, accumulate L1 diff. Grid 32 (one block per j).
// ---------------------------------------------------------------------------
__global__ __launch_bounds__(256) void merge_finalize_kernel(
    const float* __restrict__ Cpart, const float* __restrict__ Asum,
    const float* __restrict__ C_init, float* __restrict__ C_new,
    float* __restrict__ diff)
{
    __shared__ float wred[4];
    const int j = blockIdx.x;
    const int t = threadIdx.x;
    const float inv = 1.f / (Asum[j] + EPS);
    float ad = 0.f;
    #pragma unroll
    for (int dc = 0; dc < 3; ++dc) {
        int d = dc * 256 + t;
        float s = 0.f;
        #pragma unroll
        for (int ic = 0; ic < 8; ++ic)
            s += Cpart[((size_t)ic * MM + j) * DD + d];
        float c = s * inv;
        C_new[(size_t)j * DD + d] = c;
        ad += fabsf(c - C_init[(size_t)j * DD + d]);
    }
    #pragma unroll
    for (int off = 32; off >= 1; off >>= 1) ad += __shfl_xor(ad, off, 64);
    if ((t & 63) == 0) wred[t >> 6] = ad;
    __syncthreads();
    if (t == 0) atomicAdd(diff, wred[0] + wred[1] + wred[2] + wred[3]);
}

__global__ __launch_bounds__(256) void select_kernel(
    const float* __restrict__ C_new, const float* __restrict__ C_init,
    const float* __restrict__ diff, float* __restrict__ out)
{
    const int k = blockIdx.x * 256 + threadIdx.x;
    const float dv = *diff;
    out[k] = (dv > THRESH) ? C_new[k] : C_init[k];
}

// ---------------------------------------------------------------------------
extern "C" void kernel_launch(void* const* d_in, const int* in_sizes, int n_in,
                              void* d_out, int out_size, void* d_ws, size_t ws_size,
                              hipStream_t stream)
{
    const float* q      = (const float*)d_in[0];
    const float* X      = (const float*)d_in[1];
    const float* C_init = (const float*)d_in[2];
    const float* W1     = (const float*)d_in[3];
    const float* b1     = (const float*)d_in[4];
    const float* W2     = (const float*)d_in[5];
    const float* b2     = (const float*)d_in[6];

    float* out_C = (float*)d_out;                    // (M, D)
    float* out_a = (float*)d_out + (size_t)MM * DD;  // (N, M)

    float* ws = (float*)d_ws;
    _Float16* Wf    = (_Float16*)ws;                     // 983040 floats
    _Float16* Xf    = (_Float16*)(ws + 983040);          // 786432 floats
    _Float16* Arowh = (_Float16*)(ws + 983040 + 786432); // N*H fp16 = 524288 fl
    float* Brow  = ws + 983040 + 786432 + 524288;        // 16384
    float* S     = Brow + (size_t)MM * HH;               // 65536
    float* Cpart = S + (size_t)NN * MM;                  // 8*32*768 = 196608
    float* Asum  = Cpart + 196608;                       // 32
    float* diff  = Asum + 32;                            // 1 (+31 pad)
    float* Cn    = diff + 32;                            // 24576
    // total ~= 10.3 MB

    hipMemsetAsync(S, 0, (size_t)NN * MM * sizeof(float), stream);
    hipMemsetAsync(Asum, 0, 64 * sizeof(float), stream);

    prep_X_kernel<<<192, 256, 0, stream>>>(X, Xf);
    prep_W_kernel<<<120, 256, 0, stream>>>(W1, Wf);
    build_A_kernel<<<dim3(2, 64), 512, 0, stream>>>(q, Xf, Wf, Arowh);
    build_B_kernel<<<8, 256, 0, stream>>>(C_init, q, Wf, b1, Brow);
    pairwise_kernel<<<dim3(16, 32), 512, 0, stream>>>(Xf, Wf, C_init, Arowh, Brow, W2, S);
    softmax_kernel<<<256, 256, 0, stream>>>(S, b2, out_a, Asum);
    cnew_part_kernel<<<dim3(12, 8), 256, 0, stream>>>(out_a, X, Cpart);
    merge_finalize_kernel<<<32, 256, 0, stream>>>(Cpart, Asum, C_init, Cn, diff);
    select_kernel<<<96, 256, 0, stream>>>(Cn, C_init, diff, out_C);
}

// Round 9
// 192.303 us; speedup vs baseline: 3.6632x; 1.3152x over previous
//
#include <hip/hip_runtime.h>
#include <hip/hip_fp16.h>
#include <math.h>

#define NN 2048
#define MM 32
#define DD 768
#define HH 512
#define KT 24   // 768 / 32 k-tiles
#define WBLK ((size_t)KT * 16384)   // halves per frag-ordered 768x512 W block
constexpr float TEMP = 0.05f;
constexpr float THRESH = 1e-4f;
constexpr float EPS = 1e-6f;

typedef _Float16 halfx8 __attribute__((ext_vector_type(8)));
typedef float floatx4 __attribute__((ext_vector_type(4)));

__device__ __forceinline__ halfx8 habs8(halfx8 a, halfx8 b) {
    halfx8 d = a - b;
    union { halfx8 h; unsigned int u[4]; } x;
    x.h = d;
    #pragma unroll
    for (int e = 0; e < 4; ++e) x.u[e] &= 0x7FFF7FFFu;
    return x.h;
}

// ---------------------------------------------------------------------------
// prep (fused): bx<192 -> Xf (MFMA-A frag order); else -> Wf (B frag order).
// Xf[(it*24+kt)*64+lane][e] = X[it*16+(lane&15)][kt*32+(lane>>4)*8+e]
// Wf[wb][kt][nt][lane][j] = W1[wb*768+kt*32+(lane>>4)*8+j][nt*16+(lane&15)]
// ---------------------------------------------------------------------------
__global__ __launch_bounds__(256) void prep_kernel(
    const float* __restrict__ X, const float* __restrict__ W1,
    _Float16* __restrict__ Xf, _Float16* __restrict__ Wf)
{
    __shared__ float Wt[32 * 512];
    const int t = threadIdx.x;
    if (blockIdx.x < 192) {
        #pragma unroll
        for (int p = 0; p < 4; ++p) {
            int u = blockIdx.x * 1024 + p * 256 + t;
            int it = u / 1536;
            int rem = u - it * 1536;
            int kt = rem >> 6;
            int lane = rem & 63;
            int row = it * 16 + (lane & 15);
            int kb = kt * 32 + (lane >> 4) * 8;
            const float* xp = X + (size_t)row * DD + kb;
            float4 xa = *(const float4*)xp;
            float4 xb = *(const float4*)(xp + 4);
            halfx8 v;
            v[0] = (_Float16)xa.x; v[1] = (_Float16)xa.y;
            v[2] = (_Float16)xa.z; v[3] = (_Float16)xa.w;
            v[4] = (_Float16)xb.x; v[5] = (_Float16)xb.y;
            v[6] = (_Float16)xb.z; v[7] = (_Float16)xb.w;
            *(halfx8*)(Xf + (size_t)u * 8) = v;
        }
    } else {
        const int b = blockIdx.x - 192;
        const int wb = b / 24;
        const int kt = b % 24;
        const int rowbase = wb * 768;
        #pragma unroll
        for (int rep = 0; rep < 16; ++rep) {
            int idx = rep * 256 + t;
            int row = idx >> 7;
            int c4 = (idx & 127) * 4;
            *(float4*)&Wt[row * 512 + c4] =
                *(const float4*)(W1 + (size_t)(rowbase + kt * 32 + row) * HH + c4);
        }
        __syncthreads();
        #pragma unroll
        for (int g = 0; g < 8; ++g) {
            halfx8 v;
            #pragma unroll
            for (int jj = 0; jj < 8; ++jj) {
                int o = t * 64 + g * 8 + jj;
                int nt = o >> 9;
                int l  = (o >> 3) & 63;
                int j  = o & 7;
                int k  = ((l >> 4) << 3) + j;
                int n  = nt * 16 + (l & 15);
                v[jj] = (_Float16)Wt[k * 512 + n];
            }
            *(halfx8*)(Wf + (size_t)wb * WBLK + (size_t)kt * 16384 + t * 64 + g * 8) = v;
        }
    }
}

// ---------------------------------------------------------------------------
// build_A: Arowh(fp16) = X@W1a + |X-q|@W1d, prefetch-pipelined K-loop.
// Grid (4 hs-quarters, 64 by) x 512 thr; wave = 32i(rt2) x 16h (nt=hs*8+cg).
// ---------------------------------------------------------------------------
__global__ __launch_bounds__(512, 2) void build_A_kernel(
    const float* __restrict__ q, const _Float16* __restrict__ Xf,
    const _Float16* __restrict__ Wf, _Float16* __restrict__ Arowh)
{
    __shared__ _Float16 qh[DD];
    const int t = threadIdx.x;
    const int lane = t & 63;
    const int cg = t >> 6;       // 0..7
    const int q4 = lane >> 4;
    const int l16 = lane & 15;
    const int hs = blockIdx.x;   // 0..3
    const int by = blockIdx.y;   // i-tile of 32
    const int nt = hs * 8 + cg;

    for (int d = t; d < DD; d += 512) qh[d] = (_Float16)q[d];
    __syncthreads();

    const _Float16* ap0 = Xf + ((size_t)((by * 2 + 0) * 24) * 64 + lane) * 8;
    const _Float16* ap1 = Xf + ((size_t)((by * 2 + 1) * 24) * 64 + lane) * 8;
    const _Float16* bpA = Wf + (size_t)nt * 512 + (size_t)lane * 8;
    const _Float16* bpD = Wf + 3 * WBLK + (size_t)nt * 512 + (size_t)lane * 8;

    floatx4 acc[2];
    acc[0] = (floatx4)0.f; acc[1] = (floatx4)0.f;

    halfx8 Afc[2], Bac, Bdc, Afn[2], Ban, Bdn;
    Afc[0] = *(const halfx8*)ap0;
    Afc[1] = *(const halfx8*)ap1;
    Bac = *(const halfx8*)bpA;
    Bdc = *(const halfx8*)bpD;

    for (int kt = 0; kt < KT; ++kt) {
        if (kt < KT - 1) {
            Afn[0] = *(const halfx8*)(ap0 + (kt + 1) * 512);
            Afn[1] = *(const halfx8*)(ap1 + (kt + 1) * 512);
            Ban = *(const halfx8*)(bpA + (size_t)(kt + 1) * 16384);
            Bdn = *(const halfx8*)(bpD + (size_t)(kt + 1) * 16384);
        }
        halfx8 qf = *(halfx8*)&qh[kt * 32 + q4 * 8];
        #pragma unroll
        for (int rt = 0; rt < 2; ++rt) {
            halfx8 Zd = habs8(Afc[rt], qf);
            acc[rt] = __builtin_amdgcn_mfma_f32_16x16x32_f16(Afc[rt], Bac, acc[rt], 0, 0, 0);
            acc[rt] = __builtin_amdgcn_mfma_f32_16x16x32_f16(Zd, Bdc, acc[rt], 0, 0, 0);
        }
        Afc[0] = Afn[0]; Afc[1] = Afn[1]; Bac = Ban; Bdc = Bdn;
    }
    #pragma unroll
    for (int rt = 0; rt < 2; ++rt)
        #pragma unroll
        for (int reg = 0; reg < 4; ++reg) {
            int i = by * 32 + rt * 16 + q4 * 4 + reg;
            int h = nt * 16 + l16;
            Arowh[(size_t)i * HH + h] = (_Float16)acc[rt][reg];
        }
}

// ---------------------------------------------------------------------------
// build_B: Brow[j][h] = b1[h] + y@W1b + |y-q|@W1e.
// Grid 32 (one nt each), 512 thr = 8 waves kt-split (3 kt each), LDS reduce.
// ---------------------------------------------------------------------------
__global__ __launch_bounds__(512) void build_B_kernel(
    const float* __restrict__ C_init, const float* __restrict__ q,
    const _Float16* __restrict__ Wf, const float* __restrict__ b1,
    float* __restrict__ Brow)
{
    __shared__ _Float16 yh[32 * 776];
    __shared__ _Float16 qh[DD];
    __shared__ floatx4 Bred[8][2][64];
    const int t = threadIdx.x;
    const int lane = t & 63;
    const int wv = t >> 6;
    const int q4 = lane >> 4;
    const int l16 = lane & 15;
    const int nt = blockIdx.x;

    for (int r = 0; r < 32; ++r)
        for (int d = t; d < DD; d += 512)
            yh[r * 776 + d] = (_Float16)C_init[(size_t)r * DD + d];
    for (int d = t; d < DD; d += 512) qh[d] = (_Float16)q[d];
    __syncthreads();

    const _Float16* Wb = Wf + 1 * WBLK;
    const _Float16* We = Wf + 4 * WBLK;

    floatx4 acc[2];
    acc[0] = (floatx4)0.f; acc[1] = (floatx4)0.f;

    #pragma unroll
    for (int r = 0; r < 3; ++r) {
        int kt = wv + r * 8;
        halfx8 qf = *(halfx8*)&qh[kt * 32 + q4 * 8];
        size_t wo = (size_t)kt * 16384 + (size_t)nt * 512 + (size_t)lane * 8;
        halfx8 Bb = *(const halfx8*)(Wb + wo);
        halfx8 Be = *(const halfx8*)(We + wo);
        #pragma unroll
        for (int rt = 0; rt < 2; ++rt) {
            halfx8 Ab = *(halfx8*)&yh[(rt * 16 + l16) * 776 + kt * 32 + q4 * 8];
            halfx8 Ze = habs8(Ab, qf);
            acc[rt] = __builtin_amdgcn_mfma_f32_16x16x32_f16(Ab, Bb, acc[rt], 0, 0, 0);
            acc[rt] = __builtin_amdgcn_mfma_f32_16x16x32_f16(Ze, Be, acc[rt], 0, 0, 0);
        }
    }
    Bred[wv][0][lane] = acc[0];
    Bred[wv][1][lane] = acc[1];
    __syncthreads();
    if (wv < 2) {
        int rt = wv;
        floatx4 s = Bred[0][rt][lane];
        #pragma unroll
        for (int w = 1; w < 8; ++w) s += Bred[w][rt][lane];
        #pragma unroll
        for (int reg = 0; reg < 4; ++reg) {
            int j = rt * 16 + q4 * 4 + reg;
            int h = nt * 16 + l16;
            Brow[(size_t)j * HH + h] = s[reg] + b1[h];
        }
    }
}

// ---------------------------------------------------------------------------
// pairwise: P = |x_i - y_j| @ W1c, prefetch-pipelined barrier-free fp16 MFMA.
// Grid (32 it, 16 = hs + 2*jp): lin%8 = it%8 -> per-XCD ws ~2.2 MB.
// Block: 64i x 256h(hs) x 4j, 512 thr; wave = 32i(rt2) x 64h(ct4) x 4j.
// Writes per-hs partial sums to Spart (no atomics).
// ---------------------------------------------------------------------------
__global__ __launch_bounds__(512, 2) void pairwise_kernel(
    const _Float16* __restrict__ Xf, const _Float16* __restrict__ Wf,
    const float* __restrict__ Y,
    const _Float16* __restrict__ Arowh, const float* __restrict__ Brow,
    const float* __restrict__ W2, float* __restrict__ Spart)
{
    __shared__ _Float16 yh[4 * DD];
    __shared__ float Sred[4][4][64];
    const int t = threadIdx.x;
    const int lane = t & 63;
    const int wv = t >> 6;
    const int wr = wv >> 2;      // 0..1: it pair
    const int cq = wv & 3;       // 0..3: h quad of 64
    const int q4 = lane >> 4;
    const int l16 = lane & 15;
    const int i0 = blockIdx.x * 64;
    const int hs = blockIdx.y & 1;
    const int j0 = (blockIdx.y >> 1) * 4;

    for (int d = t; d < DD; d += 512) {
        #pragma unroll
        for (int jj = 0; jj < 4; ++jj)
            yh[jj * DD + d] = (_Float16)Y[(size_t)(j0 + jj) * DD + d];
    }
    __syncthreads();

    const _Float16* Wc = Wf + 2 * WBLK;
    const _Float16* ap0 = Xf + ((size_t)((blockIdx.x * 4 + wr * 2 + 0) * 24) * 64 + lane) * 8;
    const _Float16* ap1 = Xf + ((size_t)((blockIdx.x * 4 + wr * 2 + 1) * 24) * 64 + lane) * 8;
    const _Float16* bp = Wc + (size_t)(hs * 16 + cq * 4) * 512 + (size_t)lane * 8;

    floatx4 acc[4][2][4];   // [jj][rt][ct]
    #pragma unroll
    for (int jj = 0; jj < 4; ++jj)
        #pragma unroll
        for (int rt = 0; rt < 2; ++rt)
            #pragma unroll
            for (int ct = 0; ct < 4; ++ct) acc[jj][rt][ct] = (floatx4)0.f;

    halfx8 Afc[2], Bfc[4], Afn[2], Bfn[4];
    Afc[0] = *(const halfx8*)ap0;
    Afc[1] = *(const halfx8*)ap1;
    #pragma unroll
    for (int ct = 0; ct < 4; ++ct) Bfc[ct] = *(const halfx8*)(bp + ct * 512);

    for (int kt = 0; kt < KT; ++kt) {
        if (kt < KT - 1) {
            Afn[0] = *(const halfx8*)(ap0 + (kt + 1) * 512);
            Afn[1] = *(const halfx8*)(ap1 + (kt + 1) * 512);
            #pragma unroll
            for (int ct = 0; ct < 4; ++ct)
                Bfn[ct] = *(const halfx8*)(bp + (size_t)(kt + 1) * 16384 + ct * 512);
        }
        halfx8 hv[4];
        #pragma unroll
        for (int jj = 0; jj < 4; ++jj)
            hv[jj] = *(halfx8*)&yh[jj * DD + kt * 32 + q4 * 8];
        #pragma unroll
        for (int jj = 0; jj < 4; ++jj) {
            halfx8 Zf0 = habs8(Afc[0], hv[jj]);
            halfx8 Zf1 = habs8(Afc[1], hv[jj]);
            #pragma unroll
            for (int ct = 0; ct < 4; ++ct) {
                acc[jj][0][ct] = __builtin_amdgcn_mfma_f32_16x16x32_f16(Zf0, Bfc[ct], acc[jj][0][ct], 0, 0, 0);
                acc[jj][1][ct] = __builtin_amdgcn_mfma_f32_16x16x32_f16(Zf1, Bfc[ct], acc[jj][1][ct], 0, 0, 0);
            }
        }
        Afc[0] = Afn[0]; Afc[1] = Afn[1];
        #pragma unroll
        for (int ct = 0; ct < 4; ++ct) Bfc[ct] = Bfn[ct];
    }

    // epilogue: relu(P + A + B) . W2 over this wave's 64-h slice
    float w2v[4], bv[4][4];
    #pragma unroll
    for (int ct = 0; ct < 4; ++ct) {
        int h = hs * 256 + cq * 64 + ct * 16 + l16;
        w2v[ct] = W2[h];
        #pragma unroll
        for (int jj = 0; jj < 4; ++jj)
            bv[jj][ct] = Brow[(size_t)(j0 + jj) * HH + h];
    }
    #pragma unroll
    for (int rt = 0; rt < 2; ++rt)
        #pragma unroll
        for (int reg = 0; reg < 4; ++reg) {
            int row = wr * 32 + rt * 16 + q4 * 4 + reg;
            const _Float16* ap = Arowh + (size_t)(i0 + row) * HH + hs * 256 + cq * 64 + l16;
            float av[4];
            #pragma unroll
            for (int ct = 0; ct < 4; ++ct) av[ct] = (float)ap[ct * 16];
            #pragma unroll
            for (int jj = 0; jj < 4; ++jj) {
                float s = 0.f;
                #pragma unroll
                for (int ct = 0; ct < 4; ++ct) {
                    float pre = acc[jj][rt][ct][reg] + av[ct] + bv[jj][ct];
                    s = fmaf(fmaxf(pre, 0.f), w2v[ct], s);
                }
                s += __shfl_xor(s, 1, 64);
                s += __shfl_xor(s, 2, 64);
                s += __shfl_xor(s, 4, 64);
                s += __shfl_xor(s, 8, 64);
                if (l16 == 0) Sred[jj][cq][row] = s;
            }
        }
    __syncthreads();
    if (t < 256) {
        int row = t & 63, jj = t >> 6;
        float s = Sred[jj][0][row] + Sred[jj][1][row] + Sred[jj][2][row] + Sred[jj][3][row];
        Spart[((size_t)hs * NN + (i0 + row)) * MM + j0 + jj] = s;
    }
}

// ---------------------------------------------------------------------------
// softmax over j: logits from Spart halves.
// ---------------------------------------------------------------------------
__global__ __launch_bounds__(256) void softmax_kernel(
    const float* __restrict__ Spart, const float* __restrict__ b2,
    float* __restrict__ a_out)
{
    const int t = threadIdx.x;
    const int j = t & 31, r = t >> 5;
    const int i = blockIdx.x * 8 + r;
    const float b2v = b2[0];
    float s = Spart[(size_t)i * MM + j] + Spart[(size_t)(NN + i) * MM + j];
    float sig = 1.f / (1.f + expf(-(s + b2v)));
    float l = -sig * (1.0f / TEMP);
    float m = l;
    #pragma unroll
    for (int off = 16; off >= 1; off >>= 1) m = fmaxf(m, __shfl_xor(m, off, 32));
    float e = expf(l - m);
    float sum = e;
    #pragma unroll
    for (int off = 16; off >= 1; off >>= 1) sum += __shfl_xor(sum, off, 32);
    a_out[(size_t)i * MM + j] = e / sum;
}

// ---------------------------------------------------------------------------
// cnew partials over 64-i chunks + Asum partials. Grid (12, 32), 256 thr.
// ---------------------------------------------------------------------------
__global__ __launch_bounds__(256) void cnew_part_kernel(
    const float* __restrict__ a, const float* __restrict__ X,
    float* __restrict__ Cpart, float* __restrict__ Apart)
{
    const int t = threadIdx.x;
    const int dl = t & 63, jg = t >> 6;
    const int d = blockIdx.x * 64 + dl;
    const int ic = blockIdx.y;
    const int j0 = jg * 8;
    float acc[8] = {};
    float asum[8] = {};
    const int ibase = ic * 64;
    #pragma unroll 4
    for (int ii = 0; ii < 64; ++ii) {
        int i = ibase + ii;
        float xv = X[(size_t)i * DD + d];
        float4 a0 = *(const float4*)(a + (size_t)i * MM + j0);
        float4 a1 = *(const float4*)(a + (size_t)i * MM + j0 + 4);
        acc[0] = fmaf(a0.x, xv, acc[0]); asum[0] += a0.x;
        acc[1] = fmaf(a0.y, xv, acc[1]); asum[1] += a0.y;
        acc[2] = fmaf(a0.z, xv, acc[2]); asum[2] += a0.z;
        acc[3] = fmaf(a0.w, xv, acc[3]); asum[3] += a0.w;
        acc[4] = fmaf(a1.x, xv, acc[4]); asum[4] += a1.x;
        acc[5] = fmaf(a1.y, xv, acc[5]); asum[5] += a1.y;
        acc[6] = fmaf(a1.z, xv, acc[6]); asum[6] += a1.z;
        acc[7] = fmaf(a1.w, xv, acc[7]); asum[7] += a1.w;
    }
    #pragma unroll
    for (int jj = 0; jj < 8; ++jj)
        Cpart[((size_t)ic * MM + j0 + jj) * DD + d] = acc[jj];
    if (blockIdx.x == 0 && dl == 0)
        #pragma unroll
        for (int jj = 0; jj < 8; ++jj)
            Apart[ic * MM + j0 + jj] = asum[jj];
}

// ---------------------------------------------------------------------------
// merge partials -> C_new, per-j diff partial into Dpart. Grid 32.
// ---------------------------------------------------------------------------
__global__ __launch_bounds__(256) void merge_kernel(
    const float* __restrict__ Cpart, const float* __restrict__ Apart,
    const float* __restrict__ C_init, float* __restrict__ C_new,
    float* __restrict__ Dpart)
{
    __shared__ float wred[4];
    const int j = blockIdx.x;
    const int t = threadIdx.x;
    float asum = 0.f;
    #pragma unroll
    for (int ic = 0; ic < 32; ++ic) asum += Apart[ic * MM + j];
    const float inv = 1.f / (asum + EPS);
    float ad = 0.f;
    #pragma unroll
    for (int dc = 0; dc < 3; ++dc) {
        int d = dc * 256 + t;
        float s = 0.f;
        #pragma unroll
        for (int ic = 0; ic < 32; ++ic)
            s += Cpart[((size_t)ic * MM + j) * DD + d];
        float c = s * inv;
        C_new[(size_t)j * DD + d] = c;
        ad += fabsf(c - C_init[(size_t)j * DD + d]);
    }
    #pragma unroll
    for (int off = 32; off >= 1; off >>= 1) ad += __shfl_xor(ad, off, 64);
    if ((t & 63) == 0) wred[t >> 6] = ad;
    __syncthreads();
    if (t == 0) Dpart[j] = wred[0] + wred[1] + wred[2] + wred[3];
}

__global__ __launch_bounds__(256) void select_kernel(
    const float* __restrict__ C_new, const float* __restrict__ C_init,
    const float* __restrict__ Dpart, float* __restrict__ out)
{
    __shared__ float ds[32];
    const int t = threadIdx.x;
    if (t < 32) ds[t] = Dpart[t];
    __syncthreads();
    float dv = 0.f;
    #pragma unroll
    for (int jj = 0; jj < 32; ++jj) dv += ds[jj];
    const int k = blockIdx.x * 256 + t;
    out[k] = (dv > THRESH) ? C_new[k] : C_init[k];
}

// ---------------------------------------------------------------------------
extern "C" void kernel_launch(void* const* d_in, const int* in_sizes, int n_in,
                              void* d_out, int out_size, void* d_ws, size_t ws_size,
                              hipStream_t stream)
{
    const float* q      = (const float*)d_in[0];
    const float* X      = (const float*)d_in[1];
    const float* C_init = (const float*)d_in[2];
    const float* W1     = (const float*)d_in[3];
    const float* b1     = (const float*)d_in[4];
    const float* W2     = (const float*)d_in[5];
    const float* b2     = (const float*)d_in[6];

    float* out_C = (float*)d_out;                    // (M, D)
    float* out_a = (float*)d_out + (size_t)MM * DD;  // (N, M)

    float* ws = (float*)d_ws;
    _Float16* Wf    = (_Float16*)ws;                       // 983040 floats
    _Float16* Xf    = (_Float16*)(ws + 983040);            // 786432 floats
    _Float16* Arowh = (_Float16*)(ws + 1769472);           // 524288 floats
    float* Brow  = ws + 2293760;                           // 16384
    float* Spart = ws + 2310144;                           // 2*N*M = 131072
    float* Cpart = ws + 2441216;                           // 32*32*768 = 786432
    float* Apart = ws + 3227648;                           // 1024
    float* Dpart = ws + 3228672;                           // 32
    float* Cn    = ws + 3228704;                           // 24576
    // total 3253280 floats ~= 13.0 MB (<= proven 13.3 MB)

    prep_kernel<<<312, 256, 0, stream>>>(X, W1, Xf, Wf);
    build_A_kernel<<<dim3(4, 64), 512, 0, stream>>>(q, Xf, Wf, Arowh);
    build_B_kernel<<<32, 512, 0, stream>>>(C_init, q, Wf, b1, Brow);
    pairwise_kernel<<<dim3(32, 16), 512, 0, stream>>>(Xf, Wf, C_init, Arowh, Brow, W2, Spart);
    softmax_kernel<<<256, 256, 0, stream>>>(Spart, b2, out_a);
    cnew_part_kernel<<<dim3(12, 32), 256, 0, stream>>>(out_a, X, Cpart, Apart);
    merge_kernel<<<32, 256, 0, stream>>>(Cpart, Apart, C_init, Cn, Dpart);
    select_kernel<<<96, 256, 0, stream>>>(Cn, C_init, Dpart, out_C);
}

// Round 10
// 182.748 us; speedup vs baseline: 3.8547x; 1.0523x over previous
//
#include <hip/hip_runtime.h>
#include <hip/hip_fp16.h>
#include <math.h>

#define NN 2048
#define MM 32
#define DD 768
#define HH 512
#define KT 24   // 768 / 32 k-tiles
#define WBLK ((size_t)KT * 16384)   // halves per frag-ordered 768x512 W block
constexpr float TEMP = 0.05f;
constexpr float THRESH = 1e-4f;
constexpr float EPS = 1e-6f;

typedef _Float16 halfx8 __attribute__((ext_vector_type(8)));
typedef float floatx4 __attribute__((ext_vector_type(4)));

__device__ __forceinline__ halfx8 habs8(halfx8 a, halfx8 b) {
    halfx8 d = a - b;
    union { halfx8 h; unsigned int u[4]; } x;
    x.h = d;
    #pragma unroll
    for (int e = 0; e < 4; ++e) x.u[e] &= 0x7FFF7FFFu;
    return x.h;
}

// ---------------------------------------------------------------------------
// prep (fused): bx<192 -> Xf (MFMA-A frag order); else -> Wf (B frag order).
// Xf[(it*24+kt)*64+lane][e] = X[it*16+(lane&15)][kt*32+(lane>>4)*8+e]
// Wf[wb][kt][nt][lane][j] = W1[wb*768+kt*32+(lane>>4)*8+j][nt*16+(lane&15)]
// ---------------------------------------------------------------------------
__global__ __launch_bounds__(256) void prep_kernel(
    const float* __restrict__ X, const float* __restrict__ W1,
    _Float16* __restrict__ Xf, _Float16* __restrict__ Wf)
{
    __shared__ float Wt[32 * 512];
    const int t = threadIdx.x;
    if (blockIdx.x < 192) {
        #pragma unroll
        for (int p = 0; p < 4; ++p) {
            int u = blockIdx.x * 1024 + p * 256 + t;
            int it = u / 1536;
            int rem = u - it * 1536;
            int kt = rem >> 6;
            int lane = rem & 63;
            int row = it * 16 + (lane & 15);
            int kb = kt * 32 + (lane >> 4) * 8;
            const float* xp = X + (size_t)row * DD + kb;
            float4 xa = *(const float4*)xp;
            float4 xb = *(const float4*)(xp + 4);
            halfx8 v;
            v[0] = (_Float16)xa.x; v[1] = (_Float16)xa.y;
            v[2] = (_Float16)xa.z; v[3] = (_Float16)xa.w;
            v[4] = (_Float16)xb.x; v[5] = (_Float16)xb.y;
            v[6] = (_Float16)xb.z; v[7] = (_Float16)xb.w;
            *(halfx8*)(Xf + (size_t)u * 8) = v;
        }
    } else {
        const int b = blockIdx.x - 192;
        const int wb = b / 24;
        const int kt = b % 24;
        const int rowbase = wb * 768;
        #pragma unroll
        for (int rep = 0; rep < 16; ++rep) {
            int idx = rep * 256 + t;
            int row = idx >> 7;
            int c4 = (idx & 127) * 4;
            *(float4*)&Wt[row * 512 + c4] =
                *(const float4*)(W1 + (size_t)(rowbase + kt * 32 + row) * HH + c4);
        }
        __syncthreads();
        #pragma unroll
        for (int g = 0; g < 8; ++g) {
            halfx8 v;
            #pragma unroll
            for (int jj = 0; jj < 8; ++jj) {
                int o = t * 64 + g * 8 + jj;
                int nt = o >> 9;
                int l  = (o >> 3) & 63;
                int j  = o & 7;
                int k  = ((l >> 4) << 3) + j;
                int n  = nt * 16 + (l & 15);
                v[jj] = (_Float16)Wt[k * 512 + n];
            }
            *(halfx8*)(Wf + (size_t)wb * WBLK + (size_t)kt * 16384 + t * 64 + g * 8) = v;
        }
    }
}

// ---------------------------------------------------------------------------
// build_AB fused: bx<256 -> build_A (hs=bx&3, by=bx>>2); bx>=256 -> build_B
// (nt = bx-256). LDS overlaid via char buffer.
// ---------------------------------------------------------------------------
__global__ __launch_bounds__(512, 2) void build_AB_kernel(
    const float* __restrict__ q, const float* __restrict__ C_init,
    const _Float16* __restrict__ Xf, const _Float16* __restrict__ Wf,
    const float* __restrict__ b1,
    _Float16* __restrict__ Arowh, float* __restrict__ Brow)
{
    __shared__ __align__(16) char smem[67584];
    const int t = threadIdx.x;
    const int lane = t & 63;
    const int wv = t >> 6;
    const int q4 = lane >> 4;
    const int l16 = lane & 15;

    if (blockIdx.x < 256) {
        // ---- build_A: Arowh = X@W1a + |X-q|@W1d ----
        _Float16* qh = (_Float16*)smem;
        const int hs = blockIdx.x & 3;
        const int by = blockIdx.x >> 2;
        const int nt = hs * 8 + wv;

        for (int d = t; d < DD; d += 512) qh[d] = (_Float16)q[d];
        __syncthreads();

        const _Float16* ap0 = Xf + ((size_t)((by * 2 + 0) * 24) * 64 + lane) * 8;
        const _Float16* ap1 = Xf + ((size_t)((by * 2 + 1) * 24) * 64 + lane) * 8;
        const _Float16* bpA = Wf + (size_t)nt * 512 + (size_t)lane * 8;
        const _Float16* bpD = Wf + 3 * WBLK + (size_t)nt * 512 + (size_t)lane * 8;

        floatx4 acc[2];
        acc[0] = (floatx4)0.f; acc[1] = (floatx4)0.f;

        halfx8 Afc[2], Bac, Bdc, Afn[2], Ban, Bdn;
        Afc[0] = *(const halfx8*)ap0;
        Afc[1] = *(const halfx8*)ap1;
        Bac = *(const halfx8*)bpA;
        Bdc = *(const halfx8*)bpD;

        for (int kt = 0; kt < KT; ++kt) {
            if (kt < KT - 1) {
                Afn[0] = *(const halfx8*)(ap0 + (kt + 1) * 512);
                Afn[1] = *(const halfx8*)(ap1 + (kt + 1) * 512);
                Ban = *(const halfx8*)(bpA + (size_t)(kt + 1) * 16384);
                Bdn = *(const halfx8*)(bpD + (size_t)(kt + 1) * 16384);
            }
            halfx8 qf = *(halfx8*)&qh[kt * 32 + q4 * 8];
            #pragma unroll
            for (int rt = 0; rt < 2; ++rt) {
                halfx8 Zd = habs8(Afc[rt], qf);
                acc[rt] = __builtin_amdgcn_mfma_f32_16x16x32_f16(Afc[rt], Bac, acc[rt], 0, 0, 0);
                acc[rt] = __builtin_amdgcn_mfma_f32_16x16x32_f16(Zd, Bdc, acc[rt], 0, 0, 0);
            }
            Afc[0] = Afn[0]; Afc[1] = Afn[1]; Bac = Ban; Bdc = Bdn;
        }
        #pragma unroll
        for (int rt = 0; rt < 2; ++rt)
            #pragma unroll
            for (int reg = 0; reg < 4; ++reg) {
                int i = by * 32 + rt * 16 + q4 * 4 + reg;
                int h = nt * 16 + l16;
                Arowh[(size_t)i * HH + h] = (_Float16)acc[rt][reg];
            }
    } else {
        // ---- build_B: Brow[j][h] = b1[h] + y@W1b + |y-q|@W1e ----
        _Float16* yh = (_Float16*)smem;                    // 32*776 halves
        _Float16* qh = yh + 32 * 776;                      // DD halves
        floatx4* Bred = (floatx4*)(smem + (32 * 776 + DD) * 2); // [8][2][64]
        const int nt = blockIdx.x - 256;

        for (int r = 0; r < 32; ++r)
            for (int d = t; d < DD; d += 512)
                yh[r * 776 + d] = (_Float16)C_init[(size_t)r * DD + d];
        for (int d = t; d < DD; d += 512) qh[d] = (_Float16)q[d];
        __syncthreads();

        const _Float16* Wb = Wf + 1 * WBLK;
        const _Float16* We = Wf + 4 * WBLK;

        floatx4 acc[2];
        acc[0] = (floatx4)0.f; acc[1] = (floatx4)0.f;

        #pragma unroll
        for (int r = 0; r < 3; ++r) {
            int kt = wv + r * 8;
            halfx8 qf = *(halfx8*)&qh[kt * 32 + q4 * 8];
            size_t wo = (size_t)kt * 16384 + (size_t)nt * 512 + (size_t)lane * 8;
            halfx8 Bb = *(const halfx8*)(Wb + wo);
            halfx8 Be = *(const halfx8*)(We + wo);
            #pragma unroll
            for (int rt = 0; rt < 2; ++rt) {
                halfx8 Ab = *(halfx8*)&yh[(rt * 16 + l16) * 776 + kt * 32 + q4 * 8];
                halfx8 Ze = habs8(Ab, qf);
                acc[rt] = __builtin_amdgcn_mfma_f32_16x16x32_f16(Ab, Bb, acc[rt], 0, 0, 0);
                acc[rt] = __builtin_amdgcn_mfma_f32_16x16x32_f16(Ze, Be, acc[rt], 0, 0, 0);
            }
        }
        Bred[(wv * 2 + 0) * 64 + lane] = acc[0];
        Bred[(wv * 2 + 1) * 64 + lane] = acc[1];
        __syncthreads();
        if (wv < 2) {
            int rt = wv;
            floatx4 s = Bred[rt * 64 + lane];
            #pragma unroll
            for (int w = 1; w < 8; ++w) s += Bred[(w * 2 + rt) * 64 + lane];
            #pragma unroll
            for (int reg = 0; reg < 4; ++reg) {
                int j = rt * 16 + q4 * 4 + reg;
                int h = nt * 16 + l16;
                Brow[(size_t)j * HH + h] = s[reg] + b1[h];
            }
        }
    }
}

// ---------------------------------------------------------------------------
// pairwise: P = |x_i - y_j| @ W1c, barrier-free fp16 MFMA, 4 waves/SIMD.
// Block: 64i x 256h(hs) x 2j, 512 thr = 8 waves; wave = 32i(rt2) x 64h(ct4) x 2j.
// acc = 64 AGPR + ~55 VGPR -> fits 4 waves/SIMD (launch_bounds(512,4)).
// Grid (32 it64, 32 = hs + 2*jp): lin%8 = bx%8 -> per-XCD L2 ws ~2.2 MB.
// ---------------------------------------------------------------------------
__global__ __launch_bounds__(512, 4) void pairwise_kernel(
    const _Float16* __restrict__ Xf, const _Float16* __restrict__ Wf,
    const float* __restrict__ Y,
    const _Float16* __restrict__ Arowh, const float* __restrict__ Brow,
    const float* __restrict__ W2, float* __restrict__ Spart)
{
    __shared__ _Float16 yh[2 * DD];     // 3 KB
    __shared__ float Sred[2][4][64];    // 2 KB
    const int t = threadIdx.x;
    const int lane = t & 63;
    const int wv = t >> 6;
    const int wr = wv >> 2;      // 0..1: it pair
    const int cq = wv & 3;       // 0..3: h quad of 64
    const int q4 = lane >> 4;
    const int l16 = lane & 15;
    const int i0 = blockIdx.x * 64;
    const int hs = blockIdx.y & 1;
    const int j0 = (blockIdx.y >> 1) * 2;

    for (int d = t; d < DD; d += 512) {
        yh[d]      = (_Float16)Y[(size_t)j0 * DD + d];
        yh[DD + d] = (_Float16)Y[(size_t)(j0 + 1) * DD + d];
    }
    __syncthreads();

    const _Float16* Wc = Wf + 2 * WBLK;
    const _Float16* ap0 = Xf + ((size_t)((blockIdx.x * 4 + wr * 2 + 0) * 24) * 64 + lane) * 8;
    const _Float16* ap1 = Xf + ((size_t)((blockIdx.x * 4 + wr * 2 + 1) * 24) * 64 + lane) * 8;
    const _Float16* bp = Wc + (size_t)(hs * 16 + cq * 4) * 512 + (size_t)lane * 8;

    floatx4 acc[2][2][4];   // [jj][rt][ct] = 64 regs
    #pragma unroll
    for (int jj = 0; jj < 2; ++jj)
        #pragma unroll
        for (int rt = 0; rt < 2; ++rt)
            #pragma unroll
            for (int ct = 0; ct < 4; ++ct) acc[jj][rt][ct] = (floatx4)0.f;

    for (int kt = 0; kt < KT; ++kt) {
        halfx8 Af[2], Bf[4], hv[2];
        Af[0] = *(const halfx8*)(ap0 + kt * 512);
        Af[1] = *(const halfx8*)(ap1 + kt * 512);
        #pragma unroll
        for (int ct = 0; ct < 4; ++ct)
            Bf[ct] = *(const halfx8*)(bp + (size_t)kt * 16384 + ct * 512);
        hv[0] = *(halfx8*)&yh[kt * 32 + q4 * 8];
        hv[1] = *(halfx8*)&yh[DD + kt * 32 + q4 * 8];
        #pragma unroll
        for (int jj = 0; jj < 2; ++jj)
            #pragma unroll
            for (int rt = 0; rt < 2; ++rt) {
                halfx8 Zf = habs8(Af[rt], hv[jj]);
                #pragma unroll
                for (int ct = 0; ct < 4; ++ct)
                    acc[jj][rt][ct] = __builtin_amdgcn_mfma_f32_16x16x32_f16(
                        Zf, Bf[ct], acc[jj][rt][ct], 0, 0, 0);
            }
    }

    // epilogue: relu(P + A + B) . W2 over this wave's 64-h slice
    float w2v[4], bv[2][4];
    #pragma unroll
    for (int ct = 0; ct < 4; ++ct) {
        int h = hs * 256 + cq * 64 + ct * 16 + l16;
        w2v[ct] = W2[h];
        bv[0][ct] = Brow[(size_t)j0 * HH + h];
        bv[1][ct] = Brow[(size_t)(j0 + 1) * HH + h];
    }
    #pragma unroll
    for (int rt = 0; rt < 2; ++rt)
        #pragma unroll
        for (int reg = 0; reg < 4; ++reg) {
            int row = wr * 32 + rt * 16 + q4 * 4 + reg;
            const _Float16* ap = Arowh + (size_t)(i0 + row) * HH + hs * 256 + cq * 64 + l16;
            float av[4];
            #pragma unroll
            for (int ct = 0; ct < 4; ++ct) av[ct] = (float)ap[ct * 16];
            #pragma unroll
            for (int jj = 0; jj < 2; ++jj) {
                float s = 0.f;
                #pragma unroll
                for (int ct = 0; ct < 4; ++ct) {
                    float pre = acc[jj][rt][ct][reg] + av[ct] + bv[jj][ct];
                    s = fmaf(fmaxf(pre, 0.f), w2v[ct], s);
                }
                s += __shfl_xor(s, 1, 64);
                s += __shfl_xor(s, 2, 64);
                s += __shfl_xor(s, 4, 64);
                s += __shfl_xor(s, 8, 64);
                if (l16 == 0) Sred[jj][cq][row] = s;
            }
        }
    __syncthreads();
    if (t < 128) {
        int row = t & 63, jj = t >> 6;
        float s = Sred[jj][0][row] + Sred[jj][1][row] + Sred[jj][2][row] + Sred[jj][3][row];
        Spart[((size_t)hs * NN + (i0 + row)) * MM + j0 + jj] = s;
    }
}

// ---------------------------------------------------------------------------
// cnew+softmax fused: per block (dc, ic): softmax for 64 rows into LDS,
// then Cpart accumulation from LDS a. dc==0 blocks write out_a & Apart.
// Grid (12, 32), 256 thr.
// ---------------------------------------------------------------------------
__global__ __launch_bounds__(256) void cnew_sm_kernel(
    const float* __restrict__ Spart, const float* __restrict__ b2,
    const float* __restrict__ X,
    float* __restrict__ a_out, float* __restrict__ Cpart,
    float* __restrict__ Apart)
{
    __shared__ float a_s[64][36];
    const int t = threadIdx.x;
    const int dc = blockIdx.x;
    const int ic = blockIdx.y;
    const int ibase = ic * 64;
    const float b2v = b2[0];

    {   // softmax phase: 8 rows per pass
        const int j = t & 31, r = t >> 5;
        #pragma unroll
        for (int rb = 0; rb < 8; ++rb) {
            int il = rb * 8 + r;
            int i = ibase + il;
            float s = Spart[(size_t)i * MM + j] + Spart[(size_t)(NN + i) * MM + j];
            float sig = 1.f / (1.f + expf(-(s + b2v)));
            float l = -sig * (1.0f / TEMP);
            float m = l;
            #pragma unroll
            for (int off = 16; off >= 1; off >>= 1) m = fmaxf(m, __shfl_xor(m, off, 32));
            float e = expf(l - m);
            float sum = e;
            #pragma unroll
            for (int off = 16; off >= 1; off >>= 1) sum += __shfl_xor(sum, off, 32);
            a_s[il][j] = e / sum;
        }
    }
    __syncthreads();
    if (dc == 0) {
        #pragma unroll
        for (int p = 0; p < 8; ++p) {
            int k = p * 256 + t;
            a_out[(size_t)(ibase + (k >> 5)) * MM + (k & 31)] = a_s[k >> 5][k & 31];
        }
    }
    // accumulation phase
    const int dl = t & 63, jg = t >> 6;
    const int d = dc * 64 + dl;
    float acc[8] = {};
    float asum[8] = {};
    #pragma unroll 4
    for (int ii = 0; ii < 64; ++ii) {
        float xv = X[(size_t)(ibase + ii) * DD + d];
        float4 a0 = *(float4*)&a_s[ii][jg * 8];
        float4 a1 = *(float4*)&a_s[ii][jg * 8 + 4];
        acc[0] = fmaf(a0.x, xv, acc[0]); asum[0] += a0.x;
        acc[1] = fmaf(a0.y, xv, acc[1]); asum[1] += a0.y;
        acc[2] = fmaf(a0.z, xv, acc[2]); asum[2] += a0.z;
        acc[3] = fmaf(a0.w, xv, acc[3]); asum[3] += a0.w;
        acc[4] = fmaf(a1.x, xv, acc[4]); asum[4] += a1.x;
        acc[5] = fmaf(a1.y, xv, acc[5]); asum[5] += a1.y;
        acc[6] = fmaf(a1.z, xv, acc[6]); asum[6] += a1.z;
        acc[7] = fmaf(a1.w, xv, acc[7]); asum[7] += a1.w;
    }
    #pragma unroll
    for (int jj = 0; jj < 8; ++jj)
        Cpart[((size_t)ic * MM + jg * 8 + jj) * DD + d] = acc[jj];
    if (dc == 0 && dl == 0)
        #pragma unroll
        for (int jj = 0; jj < 8; ++jj)
            Apart[ic * MM + jg * 8 + jj] = asum[jj];
}

// ---------------------------------------------------------------------------
// merge partials -> C_new + per-(j,dc) diff partials. Grid (3, 32), 256 thr.
// ---------------------------------------------------------------------------
__global__ __launch_bounds__(256) void merge_kernel(
    const float* __restrict__ Cpart, const float* __restrict__ Apart,
    const float* __restrict__ C_init, float* __restrict__ C_new,
    float* __restrict__ Dpart)
{
    __shared__ float wred[4];
    const int dc = blockIdx.x;
    const int j = blockIdx.y;
    const int t = threadIdx.x;
    const int d = dc * 256 + t;
    float asum = 0.f;
    #pragma unroll
    for (int ic = 0; ic < 32; ++ic) asum += Apart[ic * MM + j];
    const float inv = 1.f / (asum + EPS);
    float s = 0.f;
    #pragma unroll
    for (int ic = 0; ic < 32; ++ic)
        s += Cpart[((size_t)ic * MM + j) * DD + d];
    float c = s * inv;
    C_new[(size_t)j * DD + d] = c;
    float ad = fabsf(c - C_init[(size_t)j * DD + d]);
    #pragma unroll
    for (int off = 32; off >= 1; off >>= 1) ad += __shfl_xor(ad, off, 64);
    if ((t & 63) == 0) wred[t >> 6] = ad;
    __syncthreads();
    if (t == 0) Dpart[j * 3 + dc] = wred[0] + wred[1] + wred[2] + wred[3];
}

__global__ __launch_bounds__(256) void select_kernel(
    const float* __restrict__ C_new, const float* __restrict__ C_init,
    const float* __restrict__ Dpart, float* __restrict__ out)
{
    __shared__ float ds[96];
    const int t = threadIdx.x;
    if (t < 96) ds[t] = Dpart[t];
    __syncthreads();
    float dv = 0.f;
    #pragma unroll
    for (int p = 0; p < 96; ++p) dv += ds[p];
    const int k = blockIdx.x * 256 + t;
    out[k] = (dv > THRESH) ? C_new[k] : C_init[k];
}

// ---------------------------------------------------------------------------
extern "C" void kernel_launch(void* const* d_in, const int* in_sizes, int n_in,
                              void* d_out, int out_size, void* d_ws, size_t ws_size,
                              hipStream_t stream)
{
    const float* q      = (const float*)d_in[0];
    const float* X      = (const float*)d_in[1];
    const float* C_init = (const float*)d_in[2];
    const float* W1     = (const float*)d_in[3];
    const float* b1     = (const float*)d_in[4];
    const float* W2     = (const float*)d_in[5];
    const float* b2     = (const float*)d_in[6];

    float* out_C = (float*)d_out;                    // (M, D)
    float* out_a = (float*)d_out + (size_t)MM * DD;  // (N, M)

    float* ws = (float*)d_ws;
    _Float16* Wf    = (_Float16*)ws;                       // 983040 floats
    _Float16* Xf    = (_Float16*)(ws + 983040);            // 786432 floats
    _Float16* Arowh = (_Float16*)(ws + 1769472);           // 524288 floats
    float* Brow  = ws + 2293760;                           // 16384
    float* Spart = ws + 2310144;                           // 2*N*M = 131072
    float* Cpart = ws + 2441216;                           // 32*32*768 = 786432
    float* Apart = ws + 3227648;                           // 1024
    float* Dpart = ws + 3228672;                           // 96
    float* Cn    = ws + 3228768;                           // 24576
    // total ~13.0 MB

    prep_kernel<<<312, 256, 0, stream>>>(X, W1, Xf, Wf);
    build_AB_kernel<<<288, 512, 0, stream>>>(q, C_init, Xf, Wf, b1, Arowh, Brow);
    pairwise_kernel<<<dim3(32, 32), 512, 0, stream>>>(Xf, Wf, C_init, Arowh, Brow, W2, Spart);
    cnew_sm_kernel<<<dim3(12, 32), 256, 0, stream>>>(Spart, b2, X, out_a, Cpart, Apart);
    merge_kernel<<<dim3(3, 32), 256, 0, stream>>>(Cpart, Apart, C_init, Cn, Dpart);
    select_kernel<<<96, 256, 0, stream>>>(Cn, C_init, Dpart, out_C);
}